// Round 1
// baseline (310.336 us; speedup 1.0000x reference)
//
#include <hip/hip_runtime.h>

// PatchEmbedder: out[b,p,:] = patch_mask[b,p] ? sum_n sum_l mask_n[b,p,l]*emb_n[ids_n[b,p,l],:] : 0
// B=8, P=1024, D=512, L=(8,7,6). One wave (64 lanes) per patch; lane holds 8
// floats (2x float4) of the D=512 row. All masks are wave-uniform -> no divergence.

#define D_DIM 512
#define NPATCH 8192  // B*P

__device__ __forceinline__ void acc_add(float4& a, const float4 b) {
    a.x += b.x; a.y += b.y; a.z += b.z; a.w += b.w;
}

template <int L>
__device__ __forceinline__ void gather_sum(const int* __restrict__ ids,
                                           const int* __restrict__ mask,
                                           const float* __restrict__ emb,
                                           int lane, float4& acc0, float4& acc1) {
#pragma unroll
    for (int l = 0; l < L; ++l) {
        if (mask[l]) {
            const float4* row = (const float4*)(emb + (size_t)ids[l] * D_DIM);
            acc_add(acc0, row[lane]);        // floats [lane*4 .. lane*4+3]
            acc_add(acc1, row[64 + lane]);   // floats [256+lane*4 ..]
        }
    }
}

__global__ __launch_bounds__(256) void patch_embed_kernel(
    const int* __restrict__ ids1, const int* __restrict__ m1, const float* __restrict__ e1,
    const int* __restrict__ ids2, const int* __restrict__ m2, const float* __restrict__ e2,
    const int* __restrict__ ids3, const int* __restrict__ m3, const float* __restrict__ e3,
    const int* __restrict__ pmask, float* __restrict__ out) {
    const int wave  = threadIdx.x >> 6;
    const int lane  = threadIdx.x & 63;
    const int patch = (blockIdx.x << 2) | wave;   // 4 waves/block, one patch each

    float4 acc0 = make_float4(0.f, 0.f, 0.f, 0.f);
    float4 acc1 = make_float4(0.f, 0.f, 0.f, 0.f);

    if (pmask[patch]) {   // wave-uniform branch
        gather_sum<8>(ids1 + patch * 8, m1 + patch * 8, e1, lane, acc0, acc1);
        gather_sum<7>(ids2 + patch * 7, m2 + patch * 7, e2, lane, acc0, acc1);
        gather_sum<6>(ids3 + patch * 6, m3 + patch * 6, e3, lane, acc0, acc1);
    }

    float4* outv = (float4*)(out + (size_t)patch * D_DIM);
    outv[lane]      = acc0;
    outv[64 + lane] = acc1;
}

extern "C" void kernel_launch(void* const* d_in, const int* in_sizes, int n_in,
                              void* d_out, int out_size, void* d_ws, size_t ws_size,
                              hipStream_t stream) {
    // setup_inputs() dict order:
    // 0 ids_1[8,1024,8] i64->int, 1 mask_1[8,1024,8] bool->int, 2 emb_1[65536,512] f32,
    // 3 ids_2[8,1024,7],          4 mask_2[8,1024,7],           5 emb_2[65536,512],
    // 6 ids_3[8,1024,6],          7 mask_3[8,1024,6],           8 emb_3[65536,512],
    // 9 patch_mask[8,1024] bool->int
    const int*   ids1  = (const int*)d_in[0];
    const int*   m1    = (const int*)d_in[1];
    const float* e1    = (const float*)d_in[2];
    const int*   ids2  = (const int*)d_in[3];
    const int*   m2    = (const int*)d_in[4];
    const float* e2    = (const float*)d_in[5];
    const int*   ids3  = (const int*)d_in[6];
    const int*   m3    = (const int*)d_in[7];
    const float* e3    = (const float*)d_in[8];
    const int*   pmask = (const int*)d_in[9];
    float* out = (float*)d_out;

    dim3 grid(NPATCH / 4);   // 2048 blocks x 4 waves = 8192 patches
    dim3 block(256);
    patch_embed_kernel<<<grid, block, 0, stream>>>(ids1, m1, e1, ids2, m2, e2,
                                                   ids3, m3, e3, pmask, out);
}